// Round 1
// baseline (13626.979 us; speedup 1.0000x reference)
//
#include <hip/hip_runtime.h>
#include <cstddef>

#define NN 512
#define BSZ 128
#define TMAXN 1024
#define STEP_F 0.01f
#define EPS_F 1e-05f
#define MATSZ (NN*NN)        // 262144
#define OUT_TN (TMAXN*NN)    // 524288
#define SKEW_SCALE 0.0078125f  // 2^-7, 7 squarings

// ---------------- small prep kernels ----------------

__global__ void prep_params(const float* __restrict__ A_raw,
                            const float* __restrict__ Theta_raw,
                            const float* __restrict__ Sigma_raw,
                            const float* __restrict__ bx_raw,
                            float* __restrict__ params,
                            float* __restrict__ theta,
                            float* __restrict__ sigma,
                            float* __restrict__ bx)
{
    int i = threadIdx.x;  // 512 threads
    if (i == 0) params[0] = fabsf(A_raw[0]) + EPS_F;
    theta[i] = fabsf(Theta_raw[i*NN + i]) + EPS_F;
    float sd = Sigma_raw[i*NN + i];
    sigma[i] = expf(-sd*sd);           // (1/G)*exp(-d^2), G=1
    bx[i] = bx_raw[i];
}

// S[z][i][j] = skew(raw_z)[i][j] * 2^-7   (z=0: U_raw, z=1: V_raw)
__global__ void build_S(const float* __restrict__ U_raw,
                        const float* __restrict__ V_raw,
                        float* __restrict__ S)
{
    int idx = blockIdx.x * 256 + threadIdx.x;   // 0 .. 2*MATSZ-1
    int z = idx >> 18;
    int rem = idx & (MATSZ - 1);
    int i = rem >> 9;
    int j = rem & (NN - 1);
    const float* src = (z == 0) ? U_raw : V_raw;
    float v = 0.0f;
    if (i < j)      v = src[i*NN + j];
    else if (i > j) v = -src[j*NN + i];
    S[idx] = v * SKEW_SCALE;
}

// P = I + S/12  (innermost Horner term, order-12 Taylor)
__global__ void init_P(const float* __restrict__ S, float* __restrict__ P)
{
    int idx = blockIdx.x * 256 + threadIdx.x;   // 0 .. 2*MATSZ-1
    int rem = idx & (MATSZ - 1);
    int i = rem >> 9;
    int j = rem & (NN - 1);
    P[idx] = S[idx] * (1.0f/12.0f) + ((i == j) ? 1.0f : 0.0f);
}

// ---------------- batched 512x512x512 fp32 matmul: C = alpha*A*B (+ I) ----------------
// 64x64 tile / block, 256 threads, 4x4 per thread, BK=16
__global__ __launch_bounds__(256) void mm_kernel(const float* __restrict__ A,
                                                 const float* __restrict__ Bm,
                                                 float* __restrict__ C,
                                                 float alpha, int addI)
{
    int z = blockIdx.z;
    A  += (size_t)z * MATSZ;
    Bm += (size_t)z * MATSZ;
    C  += (size_t)z * MATSZ;

    __shared__ float As[16][68];   // [k][m], padded (68*4B: 16B-aligned rows, bank-rotated)
    __shared__ float Bs[16][68];   // [k][n]

    int tid = threadIdx.x;
    int tx = tid & 15;
    int ty = tid >> 4;
    int row0 = blockIdx.y * 64;
    int col0 = blockIdx.x * 64;

    float acc[4][4] = {{0.f}};

    for (int k0 = 0; k0 < NN; k0 += 16) {
        // stage A tile (64 rows x 16 k), transposed into As[k][m]
        {
            int i = tid >> 2;             // 0..63 row
            int j = (tid & 3) << 2;       // 0,4,8,12 k
            float4 av = *reinterpret_cast<const float4*>(&A[(size_t)(row0 + i)*NN + k0 + j]);
            As[j+0][i] = av.x; As[j+1][i] = av.y; As[j+2][i] = av.z; As[j+3][i] = av.w;
        }
        // stage B tile (16 k x 64 cols)
        {
            int bi = tid >> 4;            // 0..15 k
            int bj = (tid & 15) << 2;     // 0..60 col
            float4 bv = *reinterpret_cast<const float4*>(&Bm[(size_t)(k0 + bi)*NN + col0 + bj]);
            *reinterpret_cast<float4*>(&Bs[bi][bj]) = bv;
        }
        __syncthreads();
#pragma unroll
        for (int k = 0; k < 16; ++k) {
            float a0 = As[k][ty], a1 = As[k][ty+16], a2 = As[k][ty+32], a3 = As[k][ty+48];
            float b0 = Bs[k][tx], b1 = Bs[k][tx+16], b2 = Bs[k][tx+32], b3 = Bs[k][tx+48];
            acc[0][0] += a0*b0; acc[0][1] += a0*b1; acc[0][2] += a0*b2; acc[0][3] += a0*b3;
            acc[1][0] += a1*b0; acc[1][1] += a1*b1; acc[1][2] += a1*b2; acc[1][3] += a1*b3;
            acc[2][0] += a2*b0; acc[2][1] += a2*b1; acc[2][2] += a2*b2; acc[2][3] += a2*b3;
            acc[3][0] += a3*b0; acc[3][1] += a3*b1; acc[3][2] += a3*b2; acc[3][3] += a3*b3;
        }
        __syncthreads();
    }

#pragma unroll
    for (int mi = 0; mi < 4; ++mi) {
        int r = row0 + ty + 16*mi;
#pragma unroll
        for (int mj = 0; mj < 4; ++mj) {
            int c = col0 + tx + 16*mj;
            float v = alpha * acc[mi][mj];
            if (addI && r == c) v += 1.0f;
            C[(size_t)r*NN + c] = v;
        }
    }
}

// Asc[i][j] = E_U[i][j]*sigma[j];  VT[i][j] = E_V[j][i]
__global__ void scale_transpose(const float* __restrict__ EU,
                                const float* __restrict__ EV,
                                const float* __restrict__ sigma,
                                float* __restrict__ Asc,
                                float* __restrict__ VT)
{
    int idx = blockIdx.x * 256 + threadIdx.x;   // 0..MATSZ-1
    int i = idx >> 9;
    int j = idx & (NN - 1);
    Asc[idx] = EU[idx] * sigma[j];
    VT[idx]  = EV[j*NN + i];
}

// Bt[k][r] = Bmm[r][k] * theta[k] / theta[r]
__global__ void finalize_Bt(const float* __restrict__ Bmm,
                            const float* __restrict__ theta,
                            float* __restrict__ Bt)
{
    int idx = blockIdx.x * 256 + threadIdx.x;   // 0..MATSZ-1
    int k = idx >> 9;
    int r = idx & (NN - 1);
    Bt[idx] = Bmm[r*NN + k] * theta[k] / theta[r];
}

// xb0 = X0 (layout [b][n]); out[b, 0, n] = X0[b][n]
__global__ void init_x(const float* __restrict__ X0,
                       float* __restrict__ xb0,
                       float* __restrict__ out)
{
    int idx = blockIdx.x * 256 + threadIdx.x;   // 0..65535
    int b = idx >> 9;
    int n = idx & (NN - 1);
    float v = X0[idx];
    xb0[idx] = v;
    out[(size_t)b * OUT_TN + n] = v;
}

// ---------------- one Euler step ----------------
// grid (16 col-groups of 8, 16 row-groups of 32), 256 threads, 1 output/thread
__global__ __launch_bounds__(256) void step_kernel(const float* __restrict__ x_in,  // [128][512]
                                                   float* __restrict__ x_out,       // [128][512]
                                                   const float* __restrict__ Bt,    // [k][r]
                                                   const float* __restrict__ params,
                                                   const float* __restrict__ bx,
                                                   float* __restrict__ out, int t)
{
    __shared__ float xs[8][516];   // relu(x[c][k]), padded stride 516 (bank-rotating)
    int tid = threadIdx.x;
    int cg = blockIdx.x;           // 0..15 -> cols cg*8..+7
    int rg = blockIdx.y;           // 0..15 -> rows rg*32..+31

    // stage relu(x) for this block's 8 columns: 8*512 floats, 4 float4/thread
#pragma unroll
    for (int q = 0; q < 4; ++q) {
        int fi = (tid + q*256) << 2;       // float index 0..16380, mult of 4
        int cc = fi >> 9;                   // 0..7
        int kk = fi & (NN - 1);
        float4 v = *reinterpret_cast<const float4*>(&x_in[(size_t)(cg*8 + cc)*NN + kk]);
        v.x = fmaxf(v.x, 0.f); v.y = fmaxf(v.y, 0.f);
        v.z = fmaxf(v.z, 0.f); v.w = fmaxf(v.w, 0.f);
        *reinterpret_cast<float4*>(&xs[cc][kk]) = v;
    }
    __syncthreads();

    int tx = tid & 7;              // col within tile
    int tr = tid >> 3;             // 0..31 row within tile
    int r = rg*32 + tr;
    int c = cg*8 + tx;

    float acc = 0.f;
#pragma unroll 8
    for (int k = 0; k < NN; ++k) {
        acc += Bt[(size_t)k*NN + r] * xs[tx][k];
    }

    float a  = params[0];
    float c0 = 1.0f - STEP_F * a;
    float xo = x_in[(size_t)c*NN + r];
    float nv = c0 * xo + STEP_F * (acc + bx[r]);
    x_out[(size_t)c*NN + r] = nv;
    out[(size_t)c * OUT_TN + (size_t)t * NN + r] = nv;
}

// ---------------- host ----------------

extern "C" void kernel_launch(void* const* d_in, const int* in_sizes, int n_in,
                              void* d_out, int out_size, void* d_ws, size_t ws_size,
                              hipStream_t stream)
{
    const float* X0        = (const float*)d_in[0];
    const float* A_raw     = (const float*)d_in[1];
    const float* Theta_raw = (const float*)d_in[2];
    const float* U_raw     = (const float*)d_in[3];
    const float* Sigma_raw = (const float*)d_in[4];
    const float* V_raw     = (const float*)d_in[5];
    const float* bx_raw    = (const float*)d_in[6];
    float* out = (float*)d_out;
    float* w   = (float*)d_ws;

    // workspace layout (floats): total ~1.575M floats ~ 6.3 MB
    float* S      = w;                       // 2*MATSZ
    float* T0     = w + 2*MATSZ;             // 2*MATSZ
    float* T1     = w + 4*MATSZ;             // 2*MATSZ
    float* params = w + 6*MATSZ;             // [0]=a
    float* theta  = params + 64;             // 512
    float* sigma  = theta + 512;             // 512
    float* bx     = sigma + 512;             // 512

    prep_params<<<1, 512, 0, stream>>>(A_raw, Theta_raw, Sigma_raw, bx_raw,
                                       params, theta, sigma, bx);
    build_S<<<2*MATSZ/256, 256, 0, stream>>>(U_raw, V_raw, S);
    init_P<<<2*MATSZ/256, 256, 0, stream>>>(S, T0);

    // Horner: P = I + (S/j) * P, j = 11..1  (order-12 Taylor of exp(S))
    float* Pa = T0; float* Pb = T1;
    for (int j = 11; j >= 1; --j) {
        mm_kernel<<<dim3(8,8,2), 256, 0, stream>>>(S, Pa, Pb, 1.0f/(float)j, 1);
        float* tmp = Pa; Pa = Pb; Pb = tmp;
    }
    // 7 squarings: exp(S*2^7) = exp(skew)
    for (int q = 0; q < 7; ++q) {
        mm_kernel<<<dim3(8,8,2), 256, 0, stream>>>(Pa, Pa, Pb, 1.0f, 0);
        float* tmp = Pa; Pa = Pb; Pb = tmp;
    }
    // Pa now holds E_U (z=0) and E_V (z=1); Pb is free scratch. S is free.

    float* Asc = S;               // MATSZ
    float* VT  = S + MATSZ;       // MATSZ
    float* Bmm = Pb;              // MATSZ
    float* Bt  = Pb + MATSZ;      // MATSZ
    float* xb0 = Pa;              // 65536
    float* xb1 = Pa + 65536;      // 65536  (overwrites E_U region - consumed already)

    scale_transpose<<<MATSZ/256, 256, 0, stream>>>(Pa, Pa + MATSZ, sigma, Asc, VT);
    mm_kernel<<<dim3(8,8,1), 256, 0, stream>>>(Asc, VT, Bmm, 1.0f, 0);
    finalize_Bt<<<MATSZ/256, 256, 0, stream>>>(Bmm, theta, Bt);

    init_x<<<BSZ*NN/256, 256, 0, stream>>>(X0, xb0, out);

    float* xp[2] = { xb0, xb1 };
    for (int t = 1; t < TMAXN; ++t) {
        step_kernel<<<dim3(16,16), 256, 0, stream>>>(xp[(t-1)&1], xp[t&1], Bt,
                                                     params, bx, out, t);
    }
}

// Round 2
// 5712.863 us; speedup vs baseline: 2.3853x; 2.3853x over previous
//
#include <hip/hip_runtime.h>
#include <cstddef>

#define NN 512
#define BSZ 128
#define TMAXN 1024
#define STEP_F 0.01f
#define EPS_F 1e-05f
#define MATSZ (NN*NN)        // 262144
#define MAT2 (2*MATSZ)
#define OUT_TN (TMAXN*NN)    // 524288
#define SKEW_SCALE 0.03125f  // 2^-5, 5 squarings

typedef __bf16 bf16x8 __attribute__((ext_vector_type(8)));
typedef float f32x4 __attribute__((ext_vector_type(4)));

// ---------------- small prep kernels ----------------

__global__ void prep_params(const float* __restrict__ A_raw,
                            const float* __restrict__ Theta_raw,
                            const float* __restrict__ Sigma_raw,
                            const float* __restrict__ bx_raw,
                            float* __restrict__ params,
                            float* __restrict__ theta,
                            float* __restrict__ sigma,
                            float* __restrict__ bx)
{
    int i = threadIdx.x;  // 512 threads
    if (i == 0) params[0] = fabsf(A_raw[0]) + EPS_F;
    theta[i] = fabsf(Theta_raw[i*NN + i]) + EPS_F;
    float sd = Sigma_raw[i*NN + i];
    sigma[i] = expf(-sd*sd);           // (1/G)*exp(-d^2), G=1
    bx[i] = bx_raw[i];
}

// S[z][i][j] = skew(raw_z)[i][j] * 2^-5
__global__ void build_S(const float* __restrict__ U_raw,
                        const float* __restrict__ V_raw,
                        float* __restrict__ S)
{
    int idx = blockIdx.x * 256 + threadIdx.x;   // 0 .. MAT2-1
    int z = idx >> 18;
    int rem = idx & (MATSZ - 1);
    int i = rem >> 9;
    int j = rem & (NN - 1);
    const float* src = (z == 0) ? U_raw : V_raw;
    float v = 0.0f;
    if (i < j)      v = src[i*NN + j];
    else if (i > j) v = -src[j*NN + i];
    S[idx] = v * SKEW_SCALE;
}

// ---------------- fp32 matmul: C = A*B (+C if accflag), batched over z ----------------
// 128x128 tile, 256 threads, 8x8 per thread, BK=8
__global__ __launch_bounds__(256) void mm128(const float* __restrict__ A,
                                             const float* __restrict__ Bm,
                                             float* __restrict__ C,
                                             int accflag)
{
    int z = blockIdx.z;
    A  += (size_t)z * MATSZ;
    Bm += (size_t)z * MATSZ;
    C  += (size_t)z * MATSZ;

    __shared__ float As[8][128];   // [k][m]
    __shared__ float Bs[8][128];   // [k][n]

    int tid = threadIdx.x;
    int row0 = blockIdx.y * 128;
    int col0 = blockIdx.x * 128;
    int tx = tid & 15;             // col-group
    int ty = tid >> 4;             // row-group
    int arow = tid >> 1, akq = (tid & 1) * 4;
    int bkr  = tid >> 5, bcol = (tid & 31) * 4;

    float acc[8][8] = {{0.f}};

    for (int k0 = 0; k0 < NN; k0 += 8) {
        float4 av = *reinterpret_cast<const float4*>(&A[(size_t)(row0 + arow)*NN + k0 + akq]);
        float4 bv = *reinterpret_cast<const float4*>(&Bm[(size_t)(k0 + bkr)*NN + col0 + bcol]);
        As[akq+0][arow] = av.x; As[akq+1][arow] = av.y;
        As[akq+2][arow] = av.z; As[akq+3][arow] = av.w;
        *reinterpret_cast<float4*>(&Bs[bkr][bcol]) = bv;
        __syncthreads();
#pragma unroll
        for (int k = 0; k < 8; ++k) {
            float a[8], b[8];
            *reinterpret_cast<float4*>(&a[0]) = *reinterpret_cast<float4*>(&As[k][ty*8]);
            *reinterpret_cast<float4*>(&a[4]) = *reinterpret_cast<float4*>(&As[k][ty*8+4]);
            *reinterpret_cast<float4*>(&b[0]) = *reinterpret_cast<float4*>(&Bs[k][tx*8]);
            *reinterpret_cast<float4*>(&b[4]) = *reinterpret_cast<float4*>(&Bs[k][tx*8+4]);
#pragma unroll
            for (int i = 0; i < 8; ++i)
#pragma unroll
                for (int j = 0; j < 8; ++j)
                    acc[i][j] += a[i]*b[j];
        }
        __syncthreads();
    }

#pragma unroll
    for (int i = 0; i < 8; ++i) {
        size_t r = (size_t)(row0 + ty*8 + i);
        float* crow = &C[r*NN + col0 + tx*8];
        float4 v0 = {acc[i][0], acc[i][1], acc[i][2], acc[i][3]};
        float4 v1 = {acc[i][4], acc[i][5], acc[i][6], acc[i][7]};
        if (accflag) {
            float4 o0 = *reinterpret_cast<const float4*>(&crow[0]);
            float4 o1 = *reinterpret_cast<const float4*>(&crow[4]);
            v0.x += o0.x; v0.y += o0.y; v0.z += o0.z; v0.w += o0.w;
            v1.x += o1.x; v1.y += o1.y; v1.z += o1.z; v1.w += o1.w;
        }
        *reinterpret_cast<float4*>(&crow[0]) = v0;
        *reinterpret_cast<float4*>(&crow[4]) = v1;
    }
}

// Q0/Q1/Q2 for Paterson-Stockmeyer order-12 Taylor of exp
__global__ void combo3(const float* __restrict__ S, const float* __restrict__ S2,
                       const float* __restrict__ S3, const float* __restrict__ S4,
                       float* __restrict__ Q0, float* __restrict__ Q1,
                       float* __restrict__ Q2)
{
    const float C0 = 1.0f, C1 = 1.0f, C2 = 0.5f, C3 = 1.0f/6.0f;
    const float C4 = 1.0f/24.0f, C5 = 1.0f/120.0f, C6 = 1.0f/720.0f, C7 = 1.0f/5040.0f;
    const float C8 = 1.0f/40320.0f, C9 = 1.0f/362880.0f, C10 = 1.0f/3628800.0f;
    const float C11 = 1.0f/39916800.0f, C12 = 1.0f/479001600.0f;
    int idx = blockIdx.x * 256 + threadIdx.x;   // 0 .. MAT2-1
    int rem = idx & (MATSZ - 1);
    int i = rem >> 9;
    int j = rem & (NN - 1);
    float d = (i == j) ? 1.0f : 0.0f;
    float s = S[idx], s2 = S2[idx], s3 = S3[idx], s4 = S4[idx];
    Q0[idx] = C0*d + C1*s + C2*s2 + C3*s3;
    Q1[idx] = C4*d + C5*s + C6*s2 + C7*s3;
    Q2[idx] = C8*d + C9*s + C10*s2 + C11*s3 + C12*s4;
}

// Asc[i][j] = E_U[i][j]*sigma[j];  VT[i][j] = E_V[j][i]
__global__ void scale_transpose(const float* __restrict__ EU,
                                const float* __restrict__ EV,
                                const float* __restrict__ sigma,
                                float* __restrict__ Asc,
                                float* __restrict__ VT)
{
    int idx = blockIdx.x * 256 + threadIdx.x;   // 0..MATSZ-1
    int i = idx >> 9;
    int j = idx & (NN - 1);
    Asc[idx] = EU[idx] * sigma[j];
    VT[idx]  = EV[j*NN + i];
}

// Bh/Bl[r][k]: bf16 hi/lo split of B[r][k] = Bmm[r][k]*theta[k]/theta[r]
__global__ void finalize_Bsplit(const float* __restrict__ Bmm,
                                const float* __restrict__ theta,
                                __bf16* __restrict__ Bh,
                                __bf16* __restrict__ Bl)
{
    int idx = blockIdx.x * 256 + threadIdx.x;   // 0..MATSZ-1
    int r = idx >> 9;
    int k = idx & (NN - 1);
    float v = Bmm[idx] * theta[k] / theta[r];
    __bf16 h = (__bf16)v;
    Bh[idx] = h;
    Bl[idx] = (__bf16)(v - (float)h);
}

// xb0 = X0 (layout [b][n]); out[b, 0, n] = X0[b][n]
__global__ void init_x(const float* __restrict__ X0,
                       float* __restrict__ xb0,
                       float* __restrict__ out)
{
    int idx = blockIdx.x * 256 + threadIdx.x;   // 0..65535
    int b = idx >> 9;
    int n = idx & (NN - 1);
    float v = X0[idx];
    xb0[idx] = v;
    out[(size_t)b * OUT_TN + n] = v;
}

// ---------------- one Euler step, MFMA bf16 hi/lo ----------------
// grid (8 col-groups of 16, 16 row-blocks of 32), 128 threads = 2 waves
__global__ __launch_bounds__(128) void step_mfma(
    const float* __restrict__ xcur,   // [128][512]
    float* __restrict__ xnxt,         // [128][512]
    const __bf16* __restrict__ Bh,    // [512][512] row-major [r][k]
    const __bf16* __restrict__ Bl,
    const float* __restrict__ params,
    const float* __restrict__ bx,
    float* __restrict__ out, int t)
{
    __shared__ bf16x8 xsv[2048];      // 32 KB: hi [0,16K), lo [16K,32K); [c][k] swizzled
    char* xs = (char*)xsv;
    int tid = threadIdx.x;
    int cg = blockIdx.x;              // 0..7  -> cols cg*16..+15
    int rb = blockIdx.y;              // 0..15 -> rows rb*32..+31

    // stage relu(x) hi/lo: thread: col c=tid&15, k-range [(tid>>4)*64, +64)
    {
        int c  = tid & 15;
        int kb = (tid >> 4) << 6;
        const float* src = xcur + (size_t)(cg*16 + c)*NN + kb;
        int cb = c * 1024;
        int sw = (c & 7) << 4;
#pragma unroll
        for (int q = 0; q < 8; ++q) {         // 8 bf16 per chunk
            float4 f0 = *reinterpret_cast<const float4*>(src + q*8);
            float4 f1 = *reinterpret_cast<const float4*>(src + q*8 + 4);
            float v[8] = {f0.x, f0.y, f0.z, f0.w, f1.x, f1.y, f1.z, f1.w};
            bf16x8 h, lo;
#pragma unroll
            for (int e = 0; e < 8; ++e) {
                float x = fmaxf(v[e], 0.0f);
                __bf16 hh = (__bf16)x;
                h[e] = hh;
                lo[e] = (__bf16)(x - (float)hh);
            }
            int koff = (kb + q*8) * 2;        // byte offset along k
            int ad = cb + (koff ^ sw);
            *reinterpret_cast<bf16x8*>(&xs[ad]) = h;
            *reinterpret_cast<bf16x8*>(&xs[16384 + ad]) = lo;
        }
    }
    __syncthreads();

    int w = tid >> 6;                 // wave 0..1
    int l = tid & 63;
    int r0 = rb*32 + w*16;            // global row base of this wave's 16-row tile
    int arow = l & 15;                // A row within tile
    int kch  = l >> 4;                // 0..3 k-chunk
    int c_l  = l & 15;                // B col within tile / C col

    f32x4 acc0 = {0,0,0,0}, acc1 = {0,0,0,0}, acc2 = {0,0,0,0};
    const __bf16* bhrow = Bh + (size_t)(r0 + arow)*NN + kch*8;
    const __bf16* blrow = Bl + (size_t)(r0 + arow)*NN + kch*8;
    int xbase = c_l * 1024;
    int xsw   = (c_l & 7) << 4;

#pragma unroll
    for (int ks = 0; ks < 16; ++ks) {
        bf16x8 ah = *reinterpret_cast<const bf16x8*>(bhrow + ks*32);
        bf16x8 al = *reinterpret_cast<const bf16x8*>(blrow + ks*32);
        int koff = (ks*32 + kch*8) * 2;
        int ad = xbase + (koff ^ xsw);
        bf16x8 xh = *reinterpret_cast<const bf16x8*>(&xs[ad]);
        bf16x8 xl = *reinterpret_cast<const bf16x8*>(&xs[16384 + ad]);
        acc0 = __builtin_amdgcn_mfma_f32_16x16x32_bf16(ah, xh, acc0, 0, 0, 0);
        acc1 = __builtin_amdgcn_mfma_f32_16x16x32_bf16(al, xh, acc1, 0, 0, 0);
        acc2 = __builtin_amdgcn_mfma_f32_16x16x32_bf16(ah, xl, acc2, 0, 0, 0);
    }

    // C/D layout: col = lane&15, row = (lane>>4)*4 + reg   [m89-verified]
    int crow = r0 + (l >> 4)*4;
    int ccol = cg*16 + c_l;
    float a  = params[0];
    float c0 = 1.0f - STEP_F * a;
    float4 xo = *reinterpret_cast<const float4*>(&xcur[(size_t)ccol*NN + crow]);
    float4 bv = *reinterpret_cast<const float4*>(&bx[crow]);
    float4 nv;
    nv.x = c0*xo.x + STEP_F*(acc0[0] + acc1[0] + acc2[0] + bv.x);
    nv.y = c0*xo.y + STEP_F*(acc0[1] + acc1[1] + acc2[1] + bv.y);
    nv.z = c0*xo.z + STEP_F*(acc0[2] + acc1[2] + acc2[2] + bv.z);
    nv.w = c0*xo.w + STEP_F*(acc0[3] + acc1[3] + acc2[3] + bv.w);
    *reinterpret_cast<float4*>(&xnxt[(size_t)ccol*NN + crow]) = nv;
    *reinterpret_cast<float4*>(&out[(size_t)ccol*OUT_TN + (size_t)t*NN + crow]) = nv;
}

// ---------------- host ----------------

extern "C" void kernel_launch(void* const* d_in, const int* in_sizes, int n_in,
                              void* d_out, int out_size, void* d_ws, size_t ws_size,
                              hipStream_t stream)
{
    const float* X0        = (const float*)d_in[0];
    const float* A_raw     = (const float*)d_in[1];
    const float* Theta_raw = (const float*)d_in[2];
    const float* U_raw     = (const float*)d_in[3];
    const float* Sigma_raw = (const float*)d_in[4];
    const float* V_raw     = (const float*)d_in[5];
    const float* bx_raw    = (const float*)d_in[6];
    float* out = (float*)d_out;

    // expm scratch lives in d_out (256 MB; fully overwritten by the steps after)
    float* S   = out;               // [2][512][512]
    float* S2  = out + 1*MAT2;
    float* S3  = out + 2*MAT2;
    float* S4  = out + 3*MAT2;
    float* Q2b = out + 4*MAT2;
    float* Q1b = out + 5*MAT2;
    float* Q0b = out + 6*MAT2;      // 7*MAT2*4B = 14.7 MB << 256 MB

    // persistent (through step phase) storage in d_ws: ~2.3 MB
    char* wsc = (char*)d_ws;
    __bf16* Bh = (__bf16*)wsc;                        // 512 KB
    __bf16* Bl = (__bf16*)(wsc + 524288);             // 512 KB
    float* xb0 = (float*)(wsc + 1048576);             // 256 KB
    float* xb1 = (float*)(wsc + 1048576 + 262144);    // 256 KB
    float* params = (float*)(wsc + 1048576 + 2*262144);
    float* theta  = params + 64;
    float* sigma  = theta + 512;
    float* bx     = sigma + 512;

    prep_params<<<1, 512, 0, stream>>>(A_raw, Theta_raw, Sigma_raw, bx_raw,
                                       params, theta, sigma, bx);
    build_S<<<MAT2/256, 256, 0, stream>>>(U_raw, V_raw, S);

    // Paterson-Stockmeyer order-12 Taylor: P = Q0 + S4*(Q1 + S4*Q2)
    mm128<<<dim3(4,4,2), 256, 0, stream>>>(S,  S,   S2,  0);   // S2 = S*S
    mm128<<<dim3(4,4,2), 256, 0, stream>>>(S2, S,   S3,  0);   // S3 = S2*S
    mm128<<<dim3(4,4,2), 256, 0, stream>>>(S2, S2,  S4,  0);   // S4 = S2*S2
    combo3<<<MAT2/256, 256, 0, stream>>>(S, S2, S3, S4, Q0b, Q1b, Q2b);
    mm128<<<dim3(4,4,2), 256, 0, stream>>>(S4, Q2b, Q1b, 1);   // R = Q1 + S4*Q2
    mm128<<<dim3(4,4,2), 256, 0, stream>>>(S4, Q1b, Q0b, 1);   // P = Q0 + S4*R
    // 5 squarings: exp(skew) = P^(2^5)
    float* Pa = Q0b; float* Pb = Q2b;
    for (int q = 0; q < 5; ++q) {
        mm128<<<dim3(4,4,2), 256, 0, stream>>>(Pa, Pa, Pb, 0);
        float* t2 = Pa; Pa = Pb; Pb = t2;
    }
    // Pa = [E_U ; E_V]

    scale_transpose<<<MATSZ/256, 256, 0, stream>>>(Pa, Pa + MATSZ, sigma,
                                                   S, S + MATSZ);     // Asc, VT
    mm128<<<dim3(4,4,1), 256, 0, stream>>>(S, S + MATSZ, S2, 0);      // Bmm = Asc*VT
    finalize_Bsplit<<<MATSZ/256, 256, 0, stream>>>(S2, theta, Bh, Bl);

    init_x<<<BSZ*NN/256, 256, 0, stream>>>(X0, xb0, out);

    float* xp[2] = { xb0, xb1 };
    for (int t = 1; t < TMAXN; ++t) {
        step_mfma<<<dim3(8,16), 128, 0, stream>>>(xp[(t-1)&1], xp[t&1], Bh, Bl,
                                                  params, bx, out, t);
    }
}